// Round 5
// baseline (133.605 us; speedup 1.0000x reference)
//
#include <hip/hip_runtime.h>
#include <math.h>

#define SS 8
#define NN 4096
#define MM 64
#define LBOX 20.0f

typedef __attribute__((ext_vector_type(8)))  short    short8;
typedef __attribute__((ext_vector_type(2)))  float    floatx2;
typedef __attribute__((ext_vector_type(4)))  float    floatx4;
typedef __attribute__((ext_vector_type(2)))  __bf16   bf16x2;

__device__ inline unsigned pkbf(float a, float b) {   // v_cvt_pk_bf16_f32 (RNE)
    bf16x2 p; p.x = (__bf16)a; p.y = (__bf16)b;
    unsigned u; __builtin_memcpy(&u, &p, 4); return u;
}

// One wave = 4 atoms (software-pipelined loop); lane = neighbor slot.
// R2 structure (VALU h2, MFMA P/q) + 2-level global prefetch of the next
// atom's neigh->pos/type gather issued during the current atom's phases.
// Wave-private LDS staging -> s_waitcnt lgkmcnt(0) instead of __syncthreads
// (doesn't drain vmcnt, so prefetches stay in flight).
__global__ __launch_bounds__(256) void desc_kernel(
    const float* __restrict__ pos,      // [S*N*3]
    const int*   __restrict__ types,    // [S*N]
    const int*   __restrict__ neigh,    // [S*N*M]
    const float* __restrict__ es1_w, const float* __restrict__ es1_b,
    const float* __restrict__ es2_w, const float* __restrict__ es2_b,
    const float* __restrict__ fs1_w, const float* __restrict__ fs1_b,
    const float* __restrict__ fs2_w, const float* __restrict__ fs2_b,
    const float* __restrict__ en1_w, const float* __restrict__ en1_b,
    const float* __restrict__ en2_w, const float* __restrict__ en2_b,
    const float* __restrict__ en3_w, const float* __restrict__ en3_b,
    float* __restrict__ out)            // [S*N*32*16]
{
    __shared__ alignas(16) unsigned short sh_h2[4][16][72]; // bf16 [wave][h][m]
    __shared__ alignas(16) unsigned short sh_rt[4][4][72];  // bf16 [wave][d][m]
    __shared__ alignas(16) float sh_PT[4][4][20];           // fp32 P^T [wave][d][h]
    __shared__ alignas(16) float sh_W3p[512];               // paired en3 for v_pk_fma
    __shared__ alignas(16) float sh_b3p[16][2];             // {b3[g], b3[g+16]}
    __shared__ alignas(16) float sh_A[4][128];              // A[g][d] flat g*4+d
    __shared__ alignas(16) float sh_vt[4][8];               // td[pair] @ en1_w

    const int tid = threadIdx.x;

    // ---------------- per-block weight staging (only block-wide sync) ----------------
    if (tid < 4) {  // species-pair table -> vt = td @ en1_w
        const float ti = (float)(tid >> 1), tj = (float)(tid & 1);
        float e[4] = {0.f, 0.f, 0.f, 0.f};
        #pragma unroll
        for (int swp = 0; swp < 2; ++swp) {
            const float a = swp ? tj : ti, b = swp ? ti : tj;
            float h[4];
            #pragma unroll
            for (int k = 0; k < 4; ++k)
                h[k] = fmaxf(a * es1_w[k] + b * es1_w[4 + k] + es1_b[k], 0.f);
            #pragma unroll
            for (int k = 0; k < 4; ++k) {
                float acc = es2_b[k];
                #pragma unroll
                for (int j = 0; j < 4; ++j) acc += h[j] * es2_w[j * 4 + k];
                e[k] += acc;
            }
        }
        float f[4];
        #pragma unroll
        for (int k = 0; k < 4; ++k) {
            float acc = fs1_b[k];
            #pragma unroll
            for (int j = 0; j < 4; ++j) acc += e[j] * fs1_w[j * 4 + k];
            f[k] = fmaxf(acc, 0.f);
        }
        float td[4];
        #pragma unroll
        for (int k = 0; k < 4; ++k) {
            float acc = fs2_b[k];
            #pragma unroll
            for (int j = 0; j < 4; ++j) acc += f[j] * fs2_w[j * 4 + k];
            td[k] = acc;
        }
        #pragma unroll
        for (int o = 0; o < 8; ++o) {
            float acc = 0.f;
            #pragma unroll
            for (int d = 0; d < 4; ++d) acc += td[d] * en1_w[d * 8 + o];
            sh_vt[tid][o] = acc;
        }
    }
    #pragma unroll
    for (int rr = 0; rr < 2; ++rr) {   // en3 paired for v_pk_fma A-step
        const int i = tid + rr * 256;
        const int hp = i >> 6, g = (i >> 2) & 15, w = i & 3;
        sh_W3p[i] = en3_w[(2 * hp + (w >> 1)) * 32 + g + 16 * (w & 1)];
    }
    if (tid < 32) sh_b3p[tid >> 1][tid & 1] = en3_b[(tid & 1) * 16 + (tid >> 1)];
    __syncthreads();

    const int wave = tid >> 6;
    const int lane = tid & 63;
    const int atomBase = blockIdx.x * 16 + wave * 4;   // 4 atoms per wave, same snapshot
    const int sbase = atomBase & ~(NN - 1);

    // ---------------- iteration-0 prefetch (2-level gather) ----------------
    int   nb_c = neigh[atomBase * MM + lane];
    int   gj_c = sbase + (nb_c < 0 ? 0 : nb_c);
    float px_c = pos[gj_c * 3 + 0];
    float py_c = pos[gj_c * 3 + 1];
    float pz_c = pos[gj_c * 3 + 2];
    int   tj_c = types[gj_c];

    #pragma unroll
    for (int a = 0; a < 4; ++a) {
        const int atom = atomBase + a;
        const int   nb  = nb_c;
        const float pxx = px_c, pyy = py_c, pzz = pz_c;
        const int   tjv = tj_c;

        // level-1 prefetch for next atom: issue immediately
        int nb_n = 0;
        if (a < 3) nb_n = neigh[(atom + 1) * MM + lane];

        // self pos/type (wave-uniform -> scalar loads)
        const float xi = pos[atom * 3 + 0];
        const float yi = pos[atom * 3 + 1];
        const float zi = pos[atom * 3 + 2];
        const int   ti = types[atom];

        // ---------------- geometry ----------------
        const int msk = nb < 0;
        float dx = pxx - xi;
        float dy = pyy - yi;
        float dz = pzz - zi;
        dx -= LBOX * rintf(dx * (1.0f / LBOX));
        dy -= LBOX * rintf(dy * (1.0f / LBOX));
        dz -= LBOX * rintf(dz * (1.0f / LBOX));
        const float r2   = fmaf(dx, dx, fmaf(dy, dy, fmaf(dz, dz, 1e-12f)));
        const float rinv = rsqrtf(r2);
        const float r    = r2 * rinv;
        const float u    = fminf(fmaxf((r - 2.0f) * 0.25f, 0.0f), 1.0f);
        const float swv  = 0.5f * __cosf(3.14159265358979323846f * u) + 0.5f;
        const float sij   = msk ? 0.0f : swv * rinv;
        const float scale = sij * rinv;
        const int   tt    = ti * 2 + tjv;

        // ---------------- h1 = relu(sij*vt[tt] + b1) ----------------
        float h1[8];
        {
            const float4 va = *(const float4*)(&sh_vt[tt][0]);
            const float4 vb = *(const float4*)(&sh_vt[tt][4]);
            h1[0] = fmaxf(fmaf(sij, va.x, en1_b[0]), 0.f);
            h1[1] = fmaxf(fmaf(sij, va.y, en1_b[1]), 0.f);
            h1[2] = fmaxf(fmaf(sij, va.z, en1_b[2]), 0.f);
            h1[3] = fmaxf(fmaf(sij, va.w, en1_b[3]), 0.f);
            h1[4] = fmaxf(fmaf(sij, vb.x, en1_b[4]), 0.f);
            h1[5] = fmaxf(fmaf(sij, vb.y, en1_b[5]), 0.f);
            h1[6] = fmaxf(fmaf(sij, vb.z, en1_b[6]), 0.f);
            h1[7] = fmaxf(fmaf(sij, vb.w, en1_b[7]), 0.f);
        }

        // ---------------- h2 = relu(h1 @ W2 + b2) -> bf16 LDS [h][m] ----------------
        #pragma unroll
        for (int k = 0; k < 16; ++k) {
            float acc = en2_b[k];                       // uniform -> s_load
            #pragma unroll
            for (int i = 0; i < 8; ++i) acc = fmaf(h1[i], en2_w[i * 16 + k], acc);
            const unsigned pk = pkbf(fmaxf(acc, 0.f), 0.f);
            sh_h2[wave][k][lane] = (unsigned short)pk;
        }
        {
            const unsigned p0 = pkbf(sij, dx * scale), p1 = pkbf(dy * scale, dz * scale);
            sh_rt[wave][0][lane] = (unsigned short)p0;
            sh_rt[wave][1][lane] = (unsigned short)(p0 >> 16);
            sh_rt[wave][2][lane] = (unsigned short)p1;
            sh_rt[wave][3][lane] = (unsigned short)(p1 >> 16);
        }

        // level-2 prefetch for next atom (nb_n has arrived by now)
        if (a < 3) {
            gj_c = sbase + (nb_n < 0 ? 0 : nb_n);
            px_c = pos[gj_c * 3 + 0];
            py_c = pos[gj_c * 3 + 1];
            pz_c = pos[gj_c * 3 + 2];
            tj_c = types[gj_c];
            nb_c = nb_n;
        }

        asm volatile("s_waitcnt lgkmcnt(0)" ::: "memory");

        // ---------------- P = H2^T R and q = 1^T R (matrix pipe) ----------------
        const int col16 = lane & 15;
        const int q4    = lane >> 4;
        const int m0    = q4 * 8;
        floatx4 cP = {0.f, 0.f, 0.f, 0.f};
        floatx4 cQ = {0.f, 0.f, 0.f, 0.f};
        const short8 ones = (short8)(short)0x3F80;
        #pragma unroll
        for (int ck = 0; ck < 2; ++ck) {
            const short8 af = *(const short8*)&sh_h2[wave][col16][ck * 32 + m0];
            const short8 bf = *(const short8*)&sh_rt[wave][col16 & 3][ck * 32 + m0];
            cP = __builtin_amdgcn_mfma_f32_16x16x32_bf16(af, bf, cP, 0, 0, 0);
            cQ = __builtin_amdgcn_mfma_f32_16x16x32_bf16(ones, bf, cQ, 0, 0, 0);
        }
        if (col16 < 4) *(floatx4*)&sh_PT[wave][col16][q4 * 4] = cP;
        const float qd = cQ[0];                    // q[lane&3]
        asm volatile("s_waitcnt lgkmcnt(0)" ::: "memory");

        // ---------------- A[g][d] = en3^T P + b3 q  (v_pk_fma pairs g,g+16) ----------------
        {
            const int g0 = lane >> 2, dd = lane & 3;
            const floatx2 b3v = *(const floatx2*)&sh_b3p[g0][0];
            floatx2 acc2 = floatx2{qd, qd} * b3v;
            #pragma unroll
            for (int h4 = 0; h4 < 4; ++h4) {
                const floatx4 pv = *(const floatx4*)&sh_PT[wave][dd][h4 * 4];
                const floatx4 wa = *(const floatx4*)&sh_W3p[(h4 * 2 + 0) * 64 + g0 * 4];
                const floatx4 wb = *(const floatx4*)&sh_W3p[(h4 * 2 + 1) * 64 + g0 * 4];
                acc2 += floatx2{pv.x, pv.x} * floatx2{wa.x, wa.y};
                acc2 += floatx2{pv.y, pv.y} * floatx2{wa.z, wa.w};
                acc2 += floatx2{pv.z, pv.z} * floatx2{wb.x, wb.y};
                acc2 += floatx2{pv.w, pv.w} * floatx2{wb.z, wb.w};
            }
            sh_A[wave][lane]      = acc2.x;   // lane == g0*4+dd
            sh_A[wave][lane + 64] = acc2.y;
        }
        asm volatile("s_waitcnt lgkmcnt(0)" ::: "memory");

        // ---------------- D[g][k] = A A[:16]^T ; coalesced nt store ----------------
        {
            const int g = lane >> 1, koff = (lane & 1) * 8;
            const floatx4 Ag = *(const floatx4*)&sh_A[wave][g * 4];
            floatx4 o0, o1;
            #pragma unroll
            for (int jj = 0; jj < 8; ++jj) {
                const floatx4 Ak = *(const floatx4*)&sh_A[wave][(koff + jj) * 4];
                const float v = fmaf(Ag.x, Ak.x, fmaf(Ag.y, Ak.y, fmaf(Ag.z, Ak.z, Ag.w * Ak.w)));
                if (jj < 4) o0[jj] = v; else o1[jj - 4] = v;
            }
            float* op = out + (size_t)atom * 512 + lane * 8;
            __builtin_nontemporal_store(o0, (floatx4*)op);
            __builtin_nontemporal_store(o1, (floatx4*)(op + 4));
        }
        // sh_A is re-written next iteration only after all lanes passed the
        // lgkmcnt(0) above; reads here complete before the next write phase's
        // own drain, and LDS ops within a wave are in-order per lane.
        asm volatile("s_waitcnt lgkmcnt(0)" ::: "memory");
    }
}

extern "C" void kernel_launch(void* const* d_in, const int* in_sizes, int n_in,
                              void* d_out, int out_size, void* d_ws, size_t ws_size,
                              hipStream_t stream) {
    const float* pos   = (const float*)d_in[0];
    const int*   typ   = (const int*)d_in[1];
    const int*   ngh   = (const int*)d_in[2];
    desc_kernel<<<dim3((SS * NN) / 16), dim3(256), 0, stream>>>(
        pos, typ, ngh,
        (const float*)d_in[3],  (const float*)d_in[4],
        (const float*)d_in[5],  (const float*)d_in[6],
        (const float*)d_in[7],  (const float*)d_in[8],
        (const float*)d_in[9],  (const float*)d_in[10],
        (const float*)d_in[11], (const float*)d_in[12],
        (const float*)d_in[13], (const float*)d_in[14],
        (const float*)d_in[15], (const float*)d_in[16],
        (float*)d_out);
}

// Round 6
// 125.143 us; speedup vs baseline: 1.0676x; 1.0676x over previous
//
#include <hip/hip_runtime.h>
#include <math.h>

#define SS 8
#define NN 4096
#define MM 64
#define LBOX 20.0f

typedef __attribute__((ext_vector_type(8)))  short    short8;
typedef __attribute__((ext_vector_type(2)))  float    floatx2;
typedef __attribute__((ext_vector_type(4)))  float    floatx4;
typedef __attribute__((ext_vector_type(2)))  __bf16   bf16x2;

__device__ inline unsigned pkbf(float a, float b) {   // v_cvt_pk_bf16_f32 (RNE)
    bf16x2 p; p.x = (__bf16)a; p.y = (__bf16)b;
    unsigned u; __builtin_memcpy(&u, &p, 4); return u;
}

// d_ws layout: [0, 524288)      posw: float4 {x,y,z,bitcast(type)} per atom (S*N = 32768)
//              [524288, ...)    weights: vt[32] | b3p[32] | W3p[512]   (fp32)
#define WS_POSW   0
#define WS_WT     (524288 / 4)     // float offset
#define WT_VT     0
#define WT_B3P    32
#define WT_W3P    64

// ---------- prep kernel: runs every launch (ws is re-poisoned). ----------
// blocks 0..127: pack posw. block 128: preprocess weights.
__global__ __launch_bounds__(256) void prep_kernel(
    const float* __restrict__ pos, const int* __restrict__ types,
    const float* __restrict__ es1_w, const float* __restrict__ es1_b,
    const float* __restrict__ es2_w, const float* __restrict__ es2_b,
    const float* __restrict__ fs1_w, const float* __restrict__ fs1_b,
    const float* __restrict__ fs2_w, const float* __restrict__ fs2_b,
    const float* __restrict__ en1_w, const float* __restrict__ en3_w,
    const float* __restrict__ en3_b, float* __restrict__ ws)
{
    const int tid = threadIdx.x;
    const int b = blockIdx.x;
    if (b < 128) {
        const int i = b * 256 + tid;
        floatx4 v;
        v.x = pos[i * 3 + 0];
        v.y = pos[i * 3 + 1];
        v.z = pos[i * 3 + 2];
        v.w = __int_as_float(types[i]);
        *((floatx4*)ws + i) = v;
        return;
    }
    float* wt = ws + WS_WT;
    if (tid < 4) {  // species-pair table -> vt = td @ en1_w
        const float ti = (float)(tid >> 1), tj = (float)(tid & 1);
        float e[4] = {0.f, 0.f, 0.f, 0.f};
        #pragma unroll
        for (int swp = 0; swp < 2; ++swp) {
            const float a = swp ? tj : ti, bb = swp ? ti : tj;
            float h[4];
            #pragma unroll
            for (int k = 0; k < 4; ++k)
                h[k] = fmaxf(a * es1_w[k] + bb * es1_w[4 + k] + es1_b[k], 0.f);
            #pragma unroll
            for (int k = 0; k < 4; ++k) {
                float acc = es2_b[k];
                #pragma unroll
                for (int j = 0; j < 4; ++j) acc += h[j] * es2_w[j * 4 + k];
                e[k] += acc;
            }
        }
        float f[4];
        #pragma unroll
        for (int k = 0; k < 4; ++k) {
            float acc = fs1_b[k];
            #pragma unroll
            for (int j = 0; j < 4; ++j) acc += e[j] * fs1_w[j * 4 + k];
            f[k] = fmaxf(acc, 0.f);
        }
        float td[4];
        #pragma unroll
        for (int k = 0; k < 4; ++k) {
            float acc = fs2_b[k];
            #pragma unroll
            for (int j = 0; j < 4; ++j) acc += f[j] * fs2_w[j * 4 + k];
            td[k] = acc;
        }
        #pragma unroll
        for (int o = 0; o < 8; ++o) {
            float acc = 0.f;
            #pragma unroll
            for (int d = 0; d < 4; ++d) acc += td[d] * en1_w[d * 8 + o];
            wt[WT_VT + tid * 8 + o] = acc;
        }
    }
    if (tid < 32)  // b3p: {b3[g], b3[g+16]} pairs
        wt[WT_B3P + tid] = en3_b[(tid & 1) * 16 + (tid >> 1)];
    #pragma unroll
    for (int rr = 0; rr < 2; ++rr) {   // en3 paired for v_pk_fma A-step
        const int i = tid + rr * 256;
        const int hp = i >> 6, g = (i >> 2) & 15, w = i & 3;
        wt[WT_W3P + i] = en3_w[(2 * hp + (w >> 1)) * 32 + g + 16 * (w & 1)];
    }
}

// ---------- main kernel: one wave per atom (R2 structure) ----------
__global__ __launch_bounds__(256) void desc_kernel(
    const float* __restrict__ ws,       // posw + preprocessed weights
    const int*   __restrict__ neigh,    // [S*N*M]
    const float* __restrict__ en1_b,
    const float* __restrict__ en2_w, const float* __restrict__ en2_b,
    float* __restrict__ out)            // [S*N*32*16]
{
    __shared__ alignas(16) unsigned short sh_h2[4][16][72]; // bf16 [wave][h][m]
    __shared__ alignas(16) unsigned short sh_rt[4][4][72];  // bf16 [wave][d][m]
    __shared__ alignas(16) float sh_PT[4][4][20];           // fp32 P^T [wave][d][h]
    __shared__ alignas(16) float sh_W3p[512];               // paired en3
    __shared__ alignas(16) float sh_b3p[16][2];
    __shared__ alignas(16) float sh_A[4][128];              // A[g][d] flat g*4+d
    __shared__ alignas(16) float sh_vt[4][8];

    const int tid = threadIdx.x;
    const float* wt = ws + WS_WT;

    // ---- prologue: pure coalesced staging, no compute ----
    if (tid < 32) {
        ((float*)sh_vt)[tid]  = wt[WT_VT + tid];
        ((float*)sh_b3p)[tid] = wt[WT_B3P + tid];
    }
    sh_W3p[tid]       = wt[WT_W3P + tid];
    sh_W3p[tid + 256] = wt[WT_W3P + 256 + tid];
    __syncthreads();

    const int wave = __builtin_amdgcn_readfirstlane(tid >> 6);
    const int lane = tid & 63;
    const int atom = __builtin_amdgcn_readfirstlane(blockIdx.x * 4 + (tid >> 6));
    const int sbase = atom & ~(NN - 1);
    const floatx4* __restrict__ pw = (const floatx4*)ws;

    // ---- gather: one dwordx4 per lane (pos+type packed) ----
    const floatx4 pi4 = pw[atom];                 // wave-uniform -> s_load
    const float xi = pi4.x, yi = pi4.y, zi = pi4.z;
    const int   ti = __float_as_int(pi4.w);

    const int nb  = neigh[atom * MM + lane];
    const int msk = nb < 0;
    const int gj  = sbase + (msk ? 0 : nb);
    const floatx4 pj4 = pw[gj];
    const int tj = __float_as_int(pj4.w);

    float dx = pj4.x - xi;
    float dy = pj4.y - yi;
    float dz = pj4.z - zi;
    dx -= LBOX * rintf(dx * (1.0f / LBOX));
    dy -= LBOX * rintf(dy * (1.0f / LBOX));
    dz -= LBOX * rintf(dz * (1.0f / LBOX));
    const float r2   = fmaf(dx, dx, fmaf(dy, dy, fmaf(dz, dz, 1e-12f)));
    const float rinv = rsqrtf(r2);
    const float r    = r2 * rinv;
    const float u    = fminf(fmaxf((r - 2.0f) * 0.25f, 0.0f), 1.0f);
    const float swv  = 0.5f * __cosf(3.14159265358979323846f * u) + 0.5f;
    const float sij   = msk ? 0.0f : swv * rinv;
    const float scale = sij * rinv;
    const int   tt    = ti * 2 + tj;

    // ---- h1 = relu(sij*vt[tt] + b1) ----
    float h1[8];
    {
        const float4 va = *(const float4*)(&sh_vt[tt][0]);
        const float4 vb = *(const float4*)(&sh_vt[tt][4]);
        h1[0] = fmaxf(fmaf(sij, va.x, en1_b[0]), 0.f);
        h1[1] = fmaxf(fmaf(sij, va.y, en1_b[1]), 0.f);
        h1[2] = fmaxf(fmaf(sij, va.z, en1_b[2]), 0.f);
        h1[3] = fmaxf(fmaf(sij, va.w, en1_b[3]), 0.f);
        h1[4] = fmaxf(fmaf(sij, vb.x, en1_b[4]), 0.f);
        h1[5] = fmaxf(fmaf(sij, vb.y, en1_b[5]), 0.f);
        h1[6] = fmaxf(fmaf(sij, vb.z, en1_b[6]), 0.f);
        h1[7] = fmaxf(fmaf(sij, vb.w, en1_b[7]), 0.f);
    }

    // ---- h2 = relu(h1 @ W2 + b2) -> bf16 LDS [h][m]; weights via s_load ----
    #pragma unroll
    for (int k = 0; k < 16; ++k) {
        float acc = en2_b[k];
        #pragma unroll
        for (int i = 0; i < 8; ++i) acc = fmaf(h1[i], en2_w[i * 16 + k], acc);
        sh_h2[wave][k][lane] = (unsigned short)pkbf(fmaxf(acc, 0.f), 0.f);
    }
    {
        const unsigned p0 = pkbf(sij, dx * scale), p1 = pkbf(dy * scale, dz * scale);
        sh_rt[wave][0][lane] = (unsigned short)p0;
        sh_rt[wave][1][lane] = (unsigned short)(p0 >> 16);
        sh_rt[wave][2][lane] = (unsigned short)p1;
        sh_rt[wave][3][lane] = (unsigned short)(p1 >> 16);
    }
    asm volatile("s_waitcnt lgkmcnt(0)" ::: "memory");   // wave-private staging

    // ---- P = H2^T R and q = 1^T R on the matrix pipe ----
    const int col16 = lane & 15;
    const int q4    = lane >> 4;
    const int m0    = q4 * 8;
    floatx4 cP = {0.f, 0.f, 0.f, 0.f};
    floatx4 cQ = {0.f, 0.f, 0.f, 0.f};
    const short8 ones = (short8)(short)0x3F80;
    #pragma unroll
    for (int ck = 0; ck < 2; ++ck) {
        const short8 af = *(const short8*)&sh_h2[wave][col16][ck * 32 + m0];
        const short8 bf = *(const short8*)&sh_rt[wave][col16 & 3][ck * 32 + m0];
        cP = __builtin_amdgcn_mfma_f32_16x16x32_bf16(af, bf, cP, 0, 0, 0);
        cQ = __builtin_amdgcn_mfma_f32_16x16x32_bf16(ones, bf, cQ, 0, 0, 0);
    }
    if (col16 < 4) *(floatx4*)&sh_PT[wave][col16][q4 * 4] = cP;
    const float qd = cQ[0];                    // q[lane&3]
    asm volatile("s_waitcnt lgkmcnt(0)" ::: "memory");

    // ---- A[g][d] = en3^T P + b3 q  (v_pk_fma pairs g,g+16) ----
    {
        const int g0 = lane >> 2, dd = lane & 3;
        const floatx2 b3v = *(const floatx2*)&sh_b3p[g0][0];
        floatx2 acc2 = floatx2{qd, qd} * b3v;
        #pragma unroll
        for (int h4 = 0; h4 < 4; ++h4) {
            const floatx4 pv = *(const floatx4*)&sh_PT[wave][dd][h4 * 4];
            const floatx4 wa = *(const floatx4*)&sh_W3p[(h4 * 2 + 0) * 64 + g0 * 4];
            const floatx4 wb = *(const floatx4*)&sh_W3p[(h4 * 2 + 1) * 64 + g0 * 4];
            acc2 += floatx2{pv.x, pv.x} * floatx2{wa.x, wa.y};
            acc2 += floatx2{pv.y, pv.y} * floatx2{wa.z, wa.w};
            acc2 += floatx2{pv.z, pv.z} * floatx2{wb.x, wb.y};
            acc2 += floatx2{pv.w, pv.w} * floatx2{wb.z, wb.w};
        }
        sh_A[wave][lane]      = acc2.x;   // lane == g0*4+dd
        sh_A[wave][lane + 64] = acc2.y;
    }
    asm volatile("s_waitcnt lgkmcnt(0)" ::: "memory");

    // ---- D[g][k] = A A[:16]^T ; coalesced nt store ----
    {
        const int g = lane >> 1, koff = (lane & 1) * 8;
        const floatx4 Ag = *(const floatx4*)&sh_A[wave][g * 4];
        floatx4 o0, o1;
        #pragma unroll
        for (int jj = 0; jj < 8; ++jj) {
            const floatx4 Ak = *(const floatx4*)&sh_A[wave][(koff + jj) * 4];
            const float v = fmaf(Ag.x, Ak.x, fmaf(Ag.y, Ak.y, fmaf(Ag.z, Ak.z, Ag.w * Ak.w)));
            if (jj < 4) o0[jj] = v; else o1[jj - 4] = v;
        }
        float* op = out + (size_t)atom * 512 + lane * 8;
        __builtin_nontemporal_store(o0, (floatx4*)op);
        __builtin_nontemporal_store(o1, (floatx4*)(op + 4));
    }
}

extern "C" void kernel_launch(void* const* d_in, const int* in_sizes, int n_in,
                              void* d_out, int out_size, void* d_ws, size_t ws_size,
                              hipStream_t stream) {
    const float* pos   = (const float*)d_in[0];
    const int*   typ   = (const int*)d_in[1];
    const int*   ngh   = (const int*)d_in[2];
    float* ws = (float*)d_ws;

    prep_kernel<<<dim3(129), dim3(256), 0, stream>>>(
        pos, typ,
        (const float*)d_in[3],  (const float*)d_in[4],
        (const float*)d_in[5],  (const float*)d_in[6],
        (const float*)d_in[7],  (const float*)d_in[8],
        (const float*)d_in[9],  (const float*)d_in[10],
        (const float*)d_in[11],                 // en1_w
        (const float*)d_in[15], (const float*)d_in[16],  // en3_w, en3_b
        ws);

    desc_kernel<<<dim3((SS * NN) / 4), dim3(256), 0, stream>>>(
        ws, ngh,
        (const float*)d_in[12],                 // en1_b
        (const float*)d_in[13], (const float*)d_in[14],  // en2_w, en2_b
        (float*)d_out);
}